// Round 6
// baseline (106.361 us; speedup 1.0000x reference)
//
#include <hip/hip_runtime.h>
#include <stdint.h>

// SKA 2D: out[b, g*8+cw, h, w] = sum_{i,j} x[b, g*8+cw, h+i-1, w+j-1] * w[b, cw, 3i+j, h, w]
// B=8, C=64, H=W=128, C_w=8, ks=3, groups=8. fp32. Memory-bound, ideal ~105 MB HBM.
//
// Block = (b, cw, 4-row tile), 128 threads (2 waves). Stage EXACTLY the tile's
// 4 rows x 8 channels into 16 KB LDS via async global_load_lds dwordx4 (pure
// linear layout, no clamping, 1.0x staging). Vertical halo rows (h0-1, h0+4)
// are fetched direct-from-global by the hl==0 / hl==3 half-waves only
// (exec-masked; these rows are staged by adjacent tiles concurrently -> L2/L3
// hits). Weights: 9 float4 regs/thread, reused across all 8 groups (exact 1x
// w traffic); image-edge taps neutralized by zeroing weights. Horizontal
// halos via wave shuffles (w4==0 / w4==31 masking also covers the lane-31/32
// row crossing).

#define SKA_W 128
#define SKA_HW (128 * 128)
#define TILE_ROWS 4

typedef float vf4 __attribute__((ext_vector_type(4)));

__global__ __launch_bounds__(128, 4) void SKA_44830868635847_kernel(
        const float* __restrict__ x,
        const float* __restrict__ wgt,
        float* __restrict__ out) {
    __shared__ float lds[8 * TILE_ROWS * SKA_W];  // 16 KiB

    const int t     = threadIdx.x;
    const int bid   = blockIdx.x;
    const int htile = bid & 31;          // 32 row-tiles of 4
    const int cw    = (bid >> 5) & 7;
    const int b     = bid >> 8;
    const int h0    = htile * TILE_ROWS;

    const int w4 = t & 31;               // 32 float4-chunks across W
    const int hl = t >> 5;               // 4 rows per block
    const int h  = h0 + hl;
    const int w0 = w4 * 4;

    // ---- async stage x: 8 channels x 4 rows x 128 cols = 1024 chunks,
    // 8 reps x 128 threads. All rows in-image -> no predication, no clamping.
    // LDS byte offset = chunk_idx*16 = wave-uniform base + lane*16.
    const float* xb = x + (size_t)(b * 64 + cw) * SKA_HW;
    const int wavebase = t & ~63;
#pragma unroll
    for (int rep = 0; rep < 8; ++rep) {
        int idx = rep * 128 + t;
        int ch  = idx >> 7;              // 128 chunks per channel (4 rows x 32)
        int rem = idx & 127;
        const float* gsrc = xb + (size_t)ch * 8 * SKA_HW + (size_t)h0 * SKA_W + rem * 4;
        __builtin_amdgcn_global_load_lds(
            (const __attribute__((address_space(1))) uint32_t*)gsrc,
            (__attribute__((address_space(3))) uint32_t*)&lds[(size_t)(rep * 128 + wavebase) * 4],
            16, 0, 0);
    }

    // ---- weights: 9 float4/thread, loaded once, reused across all 8 groups
    const float* wbase = wgt + ((size_t)(b * 8 + cw) * 9) * SKA_HW + (size_t)h * SKA_W + w0;
    vf4 wv[9];
#pragma unroll
    for (int k = 0; k < 9; ++k)
        wv[k] = *(const vf4*)(wbase + (size_t)k * SKA_HW);
    // zero image-edge taps: row h==0 has no i=0 tap, h==127 no i=2 tap
    if (h == 0)   { wv[0] = (vf4)(0.f); wv[1] = (vf4)(0.f); wv[2] = (vf4)(0.f); }
    if (h == 127) { wv[6] = (vf4)(0.f); wv[7] = (vf4)(0.f); wv[8] = (vf4)(0.f); }

    // vertical halo source row for edge threads (clamped; clamped cases have
    // zeroed weights so garbage*0 == 0)
    const bool is_top = (hl == 0), is_bot = (hl == TILE_ROWS - 1);
    int xrow_extra = is_top ? (h0 - 1 < 0 ? 0 : h0 - 1)
                            : (h0 + TILE_ROWS > 127 ? 127 : h0 + TILE_ROWS);

    __syncthreads();   // drains vmcnt (global_load_lds) before LDS reads

    // ---- compute: per group, 3 row taps (middle rows from LDS, halo rows
    // direct-from-global for the edge half-waves); horizontal halos via shuffle
    const size_t obase = (size_t)(b * 64 + cw) * SKA_HW + (size_t)h * SKA_W + w0;
    const int hu = (hl - 1 < 0) ? 0 : hl - 1;              // clamped LDS rows
    const int hd = (hl + 1 > TILE_ROWS - 1) ? TILE_ROWS - 1 : hl + 1;
#pragma unroll
    for (int g = 0; g < 8; ++g) {
        // halo row fetch (only edge half-waves; exec-masked, L2/L3-resident)
        vf4 extra = (vf4)(0.f);
        if (is_top || is_bot)
            extra = *(const vf4*)(xb + (size_t)g * 8 * SKA_HW + (size_t)xrow_extra * SKA_W + w0);

        const float* lbase = &lds[g * TILE_ROWS * SKA_W];
        vf4 m_up  = *(const vf4*)(lbase + hu * SKA_W + w0);
        vf4 m_mid = *(const vf4*)(lbase + hl * SKA_W + w0);
        vf4 m_dn  = *(const vf4*)(lbase + hd * SKA_W + w0);
        vf4 r0 = is_top ? extra : m_up;
        vf4 r2 = is_bot ? extra : m_dn;
        vf4 rows[3] = {r0, m_mid, r2};

        vf4 acc = (vf4)(0.f);
#pragma unroll
        for (int i = 0; i < 3; ++i) {
            vf4 mid = rows[i];
            // halos from lane-adjacent chunk (w4 +- 1); w4==0 / w4==31 masks
            // also neutralize the lane-31/32 row-crossing shuffles.
            float xl  = __shfl_up(mid.w, 1);
            xl  = (w4 == 0)  ? 0.f : xl;
            float xr4 = __shfl_down(mid.x, 1);
            xr4 = (w4 == 31) ? 0.f : xr4;
            vf4 wl = wv[i * 3 + 0];
            vf4 wm = wv[i * 3 + 1];
            vf4 wr = wv[i * 3 + 2];
            acc.x += wl.x * xl    + wm.x * mid.x + wr.x * mid.y;
            acc.y += wl.y * mid.x + wm.y * mid.y + wr.y * mid.z;
            acc.z += wl.z * mid.y + wm.z * mid.z + wr.z * mid.w;
            acc.w += wl.w * mid.z + wm.w * mid.w + wr.w * xr4;
        }
        *(vf4*)(out + obase + (size_t)g * 8 * SKA_HW) = acc;
    }
}

extern "C" void kernel_launch(void* const* d_in, const int* in_sizes, int n_in,
                              void* d_out, int out_size, void* d_ws, size_t ws_size,
                              hipStream_t stream) {
    const float* x   = (const float*)d_in[0];  // (8, 64, 128, 128)
    const float* wgt = (const float*)d_in[1];  // (8, 8, 9, 128, 128)
    float* out = (float*)d_out;                // (8, 64, 128, 128)

    // blocks = B * C_w * (H / TILE_ROWS) = 8*8*32 = 2048, 128 threads each
    SKA_44830868635847_kernel<<<2048, 128, 0, stream>>>(x, wgt, out);
}

// Round 7
// 103.335 us; speedup vs baseline: 1.0293x; 1.0293x over previous
//
#include <hip/hip_runtime.h>
#include <stdint.h>

// SKA 2D: out[b, g*8+cw, h, w] = sum_{i,j} x[b, g*8+cw, h+i-1, w+j-1] * w[b, cw, 3i+j, h, w]
// B=8, C=64, H=W=128, C_w=8, ks=3, groups=8. fp32. Memory-bound, ideal ~105 MB HBM.
//
// R5 base (best measured): block = (b, cw, 8-row tile), 256 threads. This
// round: stage EXACTLY the tile's 8 rows x 8 channels into 32 KB LDS via
// async global_load_lds dwordx4 (1.0x staging, pure linear, no predication).
// Vertical halo rows (h0-1, h0+8) are prefetched into REGISTERS for all 8
// groups BEFORE the barrier, by the hl==0 / hl==7 half-waves only (coalesced,
// L2/L3-resident since adjacent tiles stage those rows). Weights: 9 float4
// regs/thread reused across all 8 groups (exact 1x w traffic); image-edge
// taps neutralized by zeroed weights (clamped halo = garbage * 0). Horizontal
// halos via wave shuffles (w4==0 / w4==31 masks also cover the lane-31/32
// row crossing).

#define SKA_W 128
#define SKA_HW (128 * 128)
#define TILE_ROWS 8

typedef float vf4 __attribute__((ext_vector_type(4)));

__global__ __launch_bounds__(256, 4) void SKA_44830868635847_kernel(
        const float* __restrict__ x,
        const float* __restrict__ wgt,
        float* __restrict__ out) {
    __shared__ float lds[8 * TILE_ROWS * SKA_W];  // 32 KiB

    const int t     = threadIdx.x;
    const int bid   = blockIdx.x;
    const int htile = bid & 15;          // 16 row-tiles of 8
    const int cw    = (bid >> 4) & 7;
    const int b     = bid >> 7;
    const int h0    = htile * TILE_ROWS;

    const int w4 = t & 31;               // 32 float4-chunks across W
    const int hl = t >> 5;               // 8 rows per block
    const int h  = h0 + hl;
    const int w0 = w4 * 4;

    // ---- async stage x: 8 channels x 8 rows x 128 cols = 2048 chunks,
    // 8 reps x 256 threads. All rows in-image -> no predication.
    // LDS byte offset = chunk_idx*16 = wave-uniform base + lane*16.
    const float* xb = x + (size_t)(b * 64 + cw) * SKA_HW;
    const int wavebase = t & ~63;
#pragma unroll
    for (int rep = 0; rep < 8; ++rep) {
        int idx = rep * 256 + t;
        int ch  = idx >> 8;              // 256 chunks per channel (8 rows x 32)
        int rem = idx & 255;             // rem*4 spans the 8x128 row block
        const float* gsrc = xb + (size_t)ch * 8 * SKA_HW + (size_t)h0 * SKA_W + rem * 4;
        __builtin_amdgcn_global_load_lds(
            (const __attribute__((address_space(1))) uint32_t*)gsrc,
            (__attribute__((address_space(3))) uint32_t*)&lds[(size_t)(rep * 256 + wavebase) * 4],
            16, 0, 0);
    }

    // ---- vertical halo prefetch (edge half-waves only), BEFORE the barrier
    // so the latency overlaps the staging DMA. Clamped rows pair with zeroed
    // weights below.
    const bool is_top = (hl == 0), is_bot = (hl == TILE_ROWS - 1);
    vf4 halo[8];
    if (is_top || is_bot) {
        int xrow = is_top ? (h0 > 0 ? h0 - 1 : 0)
                          : (h0 + TILE_ROWS < 128 ? h0 + TILE_ROWS : 127);
#pragma unroll
        for (int g = 0; g < 8; ++g)
            halo[g] = *(const vf4*)(xb + (size_t)g * 8 * SKA_HW + (size_t)xrow * SKA_W + w0);
    }

    // ---- weights: 9 float4/thread, loaded once, reused across all 8 groups
    const float* wbase = wgt + ((size_t)(b * 8 + cw) * 9) * SKA_HW + (size_t)h * SKA_W + w0;
    vf4 wv[9];
#pragma unroll
    for (int k = 0; k < 9; ++k)
        wv[k] = *(const vf4*)(wbase + (size_t)k * SKA_HW);
    // zero image-edge taps: row h==0 has no i=0 tap, h==127 no i=2 tap
    if (h == 0)   { wv[0] = (vf4)(0.f); wv[1] = (vf4)(0.f); wv[2] = (vf4)(0.f); }
    if (h == 127) { wv[6] = (vf4)(0.f); wv[7] = (vf4)(0.f); wv[8] = (vf4)(0.f); }

    __syncthreads();   // drains vmcnt (global_load_lds) before LDS reads

    // ---- compute: per group, 3 row taps (interior rows from LDS, edge rows
    // from the prefetched halo regs); horizontal halos via shuffle
    const size_t obase = (size_t)(b * 64 + cw) * SKA_HW + (size_t)h * SKA_W + w0;
    const int hu = hl ? hl - 1 : 0;                        // clamped (in-bounds)
    const int hd = (hl < TILE_ROWS - 1) ? hl + 1 : TILE_ROWS - 1;
#pragma unroll
    for (int g = 0; g < 8; ++g) {
        const float* lbase = &lds[g * TILE_ROWS * SKA_W];
        vf4 lu = *(const vf4*)(lbase + hu * SKA_W + w0);
        vf4 lm = *(const vf4*)(lbase + hl * SKA_W + w0);
        vf4 ln = *(const vf4*)(lbase + hd * SKA_W + w0);
        vf4 rows[3];
        rows[0] = is_top ? halo[g] : lu;
        rows[1] = lm;
        rows[2] = is_bot ? halo[g] : ln;

        vf4 acc = (vf4)(0.f);
#pragma unroll
        for (int i = 0; i < 3; ++i) {
            vf4 mid = rows[i];
            // halos from lane-adjacent chunk (w4 +- 1); w4==0 / w4==31 masks
            // also neutralize the lane-31/32 row-crossing shuffles.
            float xl  = __shfl_up(mid.w, 1);
            xl  = (w4 == 0)  ? 0.f : xl;
            float xr4 = __shfl_down(mid.x, 1);
            xr4 = (w4 == 31) ? 0.f : xr4;
            vf4 wl = wv[i * 3 + 0];
            vf4 wm = wv[i * 3 + 1];
            vf4 wr = wv[i * 3 + 2];
            acc.x += wl.x * xl    + wm.x * mid.x + wr.x * mid.y;
            acc.y += wl.y * mid.x + wm.y * mid.y + wr.y * mid.z;
            acc.z += wl.z * mid.y + wm.z * mid.z + wr.z * mid.w;
            acc.w += wl.w * mid.z + wm.w * mid.w + wr.w * xr4;
        }
        *(vf4*)(out + obase + (size_t)g * 8 * SKA_HW) = acc;
    }
}

extern "C" void kernel_launch(void* const* d_in, const int* in_sizes, int n_in,
                              void* d_out, int out_size, void* d_ws, size_t ws_size,
                              hipStream_t stream) {
    const float* x   = (const float*)d_in[0];  // (8, 64, 128, 128)
    const float* wgt = (const float*)d_in[1];  // (8, 8, 9, 128, 128)
    float* out = (float*)d_out;                // (8, 64, 128, 128)

    // blocks = B * C_w * (H / TILE_ROWS) = 8*8*16 = 1024, 256 threads each
    SKA_44830868635847_kernel<<<1024, 256, 0, stream>>>(x, wgt, out);
}